// Round 2
// baseline (440.138 us; speedup 1.0000x reference)
//
#include <hip/hip_runtime.h>

#define BS 16
#define TS 2048
#define H 1024
#define MT_LEN 1024
#define NCHUNK 64
#define CHUNK_T (TS / NCHUNK)   // 32
#define SCALE 0.03125f          // 1/sqrt(1024)
#define NEG -10000.0f

// ---------------- K1: partial masked sums of hidden_states over t ----------------
// grid (NCHUNK, BS), block 256. Each block: one (b, t-chunk), covers all H via float4.
__global__ __launch_bounds__(256)
void k1_hidden_partial(const float* __restrict__ hs,
                       const int* __restrict__ am,
                       float* __restrict__ pA) {
    const int c = blockIdx.x, b = blockIdx.y;
    const int tid = threadIdx.x;
    const int h4 = tid * 4;
    __shared__ float ms[CHUNK_T];
    if (tid < CHUNK_T) ms[tid] = (float)am[b * TS + c * CHUNK_T + tid];
    __syncthreads();
    const float* base = hs + ((size_t)(b * TS + c * CHUNK_T)) * H + h4;
    float4 acc = {0.f, 0.f, 0.f, 0.f};
#pragma unroll 4
    for (int t = 0; t < CHUNK_T; ++t) {
        float m = ms[t];
        float4 v = *(const float4*)(base + (size_t)t * H);
        acc.x += m * v.x; acc.y += m * v.y; acc.z += m * v.z; acc.w += m * v.w;
    }
    *(float4*)(pA + ((size_t)(b * NCHUNK + c)) * H + h4) = acc;
}

// ---------------- K3: combine partials -> avg (LDS) -> q = Wq·avg + bq ----------------
// grid (4, BS), block 256; each thread owns one output row-dot.
__global__ __launch_bounds__(256)
void k3_q(const float* __restrict__ pA, const int* __restrict__ am,
          const float* __restrict__ Wq, const float* __restrict__ bq,
          float* __restrict__ q) {
    const int ic = blockIdx.x, b = blockIdx.y;
    const int tid = threadIdx.x;
    __shared__ float avs[H];
    __shared__ float red[256];
    // mask count
    int s = 0;
    for (int t = tid; t < TS; t += 256) s += am[b * TS + t];
    red[tid] = (float)s;
    __syncthreads();
    for (int o = 128; o > 0; o >>= 1) { if (tid < o) red[tid] += red[tid + o]; __syncthreads(); }
    const float inv = 1.0f / red[0];
    // combine partials -> avg in LDS
    const int h4 = tid * 4;
    float4 acc = {0.f, 0.f, 0.f, 0.f};
    for (int c = 0; c < NCHUNK; ++c) {
        float4 v = *(const float4*)(pA + ((size_t)(b * NCHUNK + c)) * H + h4);
        acc.x += v.x; acc.y += v.y; acc.z += v.z; acc.w += v.w;
    }
    avs[h4] = acc.x * inv; avs[h4 + 1] = acc.y * inv;
    avs[h4 + 2] = acc.z * inv; avs[h4 + 3] = acc.w * inv;
    __syncthreads();
    // q row-dot
    const int i = ic * 256 + tid;
    const float* row = Wq + (size_t)i * H;
    float a = 0.f;
    for (int j = 0; j < H; j += 4) {
        float4 w = *(const float4*)(row + j);
        a += w.x * avs[j] + w.y * avs[j + 1] + w.z * avs[j + 2] + w.w * avs[j + 3];
    }
    q[b * H + i] = a + bq[i];
}

// ---------------- K4: qk[b,j] = sum_i q[b,i]*Wk[i,j]; qbk[b] = dot(q[b],bk) ----------------
// grid (4, BS), block 256; threads over j -> coalesced Wk row reads.
__global__ __launch_bounds__(256)
void k4_qk(const float* __restrict__ q, const float* __restrict__ Wk,
           const float* __restrict__ bk, float* __restrict__ qk,
           float* __restrict__ qbk) {
    const int jc = blockIdx.x, b = blockIdx.y;
    const int tid = threadIdx.x;
    __shared__ float qs[H];
    for (int i = tid; i < H; i += 256) qs[i] = q[b * H + i];
    __syncthreads();
    const int j = jc * 256 + tid;
    float acc = 0.f;
    for (int i = 0; i < H; ++i) acc += qs[i] * Wk[(size_t)i * H + j];
    qk[b * H + j] = acc;
    if (jc == 0) {  // uniform branch per block
        __shared__ float red[256];
        float s = 0.f;
        for (int i = tid; i < H; i += 256) s += qs[i] * bk[i];
        red[tid] = s;
        __syncthreads();
        for (int o = 128; o > 0; o >>= 1) { if (tid < o) red[tid] += red[tid + o]; __syncthreads(); }
        if (tid == 0) qbk[b] = red[0];
    }
}

// ---------------- K5: scores[b,t] = mask ? SCALE*(emb[b,t]·qk[b] + qbk[b]) : NEG ----------------
// grid (NCHUNK, BS), block 256 = 4 waves; each wave computes CHUNK_T/4 token dots.
__global__ __launch_bounds__(256)
void k5_scores(const float* __restrict__ emb, const int* __restrict__ am,
               const float* __restrict__ qk, const float* __restrict__ qbk,
               float* __restrict__ scores) {
    const int c = blockIdx.x, b = blockIdx.y;
    const int tid = threadIdx.x;
    const int wave = tid >> 6, lane = tid & 63;
    __shared__ float qks[H];
    for (int j = tid; j < H; j += 256) qks[j] = qk[b * H + j];
    __syncthreads();
    const float qb = qbk[b];
    const int tbase = c * CHUNK_T + wave * (CHUNK_T / 4);
    for (int tt = 0; tt < CHUNK_T / 4; ++tt) {
        const int t = tbase + tt;
        const float* e = emb + ((size_t)(b * TS + t)) * H;
        float acc = 0.f;
#pragma unroll
        for (int u = 0; u < 4; ++u) {
            const int j = lane * 4 + u * 256;
            float4 v = *(const float4*)(e + j);
            acc += v.x * qks[j] + v.y * qks[j + 1] + v.z * qks[j + 2] + v.w * qks[j + 3];
        }
#pragma unroll
        for (int o = 32; o > 0; o >>= 1) acc += __shfl_xor(acc, o);
        if (lane == 0) {
            scores[b * TS + t] = (am[b * TS + t] != 0) ? (acc + qb) * SCALE : NEG;
        }
    }
}

// ---------------- K6: softmax over t; write probas (ws) + mt/src outputs ----------------
__global__ __launch_bounds__(256)
void k6_softmax(const float* __restrict__ scores, const int* __restrict__ am,
                const int* __restrict__ fs, float* __restrict__ probas,
                float* __restrict__ out) {
    const int b = blockIdx.x;
    const int tid = threadIdx.x;
    __shared__ float red[256];
    float local[8];
    float mx = -3.4e38f;
#pragma unroll
    for (int u = 0; u < 8; ++u) {
        local[u] = scores[b * TS + tid + u * 256];
        mx = fmaxf(mx, local[u]);
    }
    red[tid] = mx;
    __syncthreads();
    for (int o = 128; o > 0; o >>= 1) { if (tid < o) red[tid] = fmaxf(red[tid], red[tid + o]); __syncthreads(); }
    mx = red[0];
    __syncthreads();
    float sum = 0.f;
#pragma unroll
    for (int u = 0; u < 8; ++u) { local[u] = __expf(local[u] - mx); sum += local[u]; }
    red[tid] = sum;
    __syncthreads();
    for (int o = 128; o > 0; o >>= 1) { if (tid < o) red[tid] += red[tid + o]; __syncthreads(); }
    const float inv = 1.0f / red[0];
#pragma unroll
    for (int u = 0; u < 8; ++u) {
        const int t = tid + u * 256;
        const float p = local[u] * inv;
        probas[b * TS + t] = p;
        const int a = am[b * TS + t];
        const int f = fs[b * TS + t];
        if (t < MT_LEN)
            out[BS * H + b * MT_LEN + t] = p * (float)(a * f);
        else
            out[BS * H + BS * MT_LEN + b * (TS - MT_LEN) + (t - MT_LEN)] = p * (float)(a * (1 - f));
    }
}

// ---------------- K7: partial e_comb[b,h] = sum_t p[b,t]*emb[b,t,h] ----------------
__global__ __launch_bounds__(256)
void k7_wemb(const float* __restrict__ emb, const float* __restrict__ probas,
             float* __restrict__ pC) {
    const int c = blockIdx.x, b = blockIdx.y;
    const int tid = threadIdx.x;
    __shared__ float ps[CHUNK_T];
    if (tid < CHUNK_T) ps[tid] = probas[b * TS + c * CHUNK_T + tid];
    __syncthreads();
    const int h4 = tid * 4;
    const float* base = emb + ((size_t)(b * TS + c * CHUNK_T)) * H + h4;
    float4 acc = {0.f, 0.f, 0.f, 0.f};
#pragma unroll 4
    for (int t = 0; t < CHUNK_T; ++t) {
        const float p = ps[t];
        float4 v = *(const float4*)(base + (size_t)t * H);
        acc.x += p * v.x; acc.y += p * v.y; acc.z += p * v.z; acc.w += p * v.w;
    }
    *(float4*)(pC + ((size_t)(b * NCHUNK + c)) * H + h4) = acc;
}

// ---------------- K8: combine partials; combined[b,i] = dot(Wv[i,:], e_comb[b,:]) + bv[i] ----------------
__global__ __launch_bounds__(256)
void k8_combined(const float* __restrict__ pC, const float* __restrict__ Wv,
                 const float* __restrict__ bv, float* __restrict__ out) {
    const int ic = blockIdx.x, b = blockIdx.y;
    const int tid = threadIdx.x;
    __shared__ float es[H];
    const int h4 = tid * 4;
    float4 acc = {0.f, 0.f, 0.f, 0.f};
    for (int c = 0; c < NCHUNK; ++c) {
        float4 v = *(const float4*)(pC + ((size_t)(b * NCHUNK + c)) * H + h4);
        acc.x += v.x; acc.y += v.y; acc.z += v.z; acc.w += v.w;
    }
    *(float4*)(&es[h4]) = acc;
    __syncthreads();
    const int i = ic * 256 + tid;
    const float* row = Wv + (size_t)i * H;
    float a = 0.f;
    for (int j = 0; j < H; j += 4) {
        float4 w = *(const float4*)(row + j);
        a += w.x * es[j] + w.y * es[j + 1] + w.z * es[j + 2] + w.w * es[j + 3];
    }
    out[b * H + i] = a + bv[i];
}

extern "C" void kernel_launch(void* const* d_in, const int* in_sizes, int n_in,
                              void* d_out, int out_size, void* d_ws, size_t ws_size,
                              hipStream_t stream) {
    const float* hs  = (const float*)d_in[0];   // hidden_states (16,2048,1024)
    const float* emb = (const float*)d_in[1];   // embeddings    (16,2048,1024)
    const int*   am  = (const int*)d_in[2];     // attention_mask (16,2048)
    const int*   fs  = (const int*)d_in[3];     // first_sentence_mask (16,2048)
    // d_in[4]: first_piece_mask (unused)
    const float* Wq  = (const float*)d_in[5];
    const float* bq  = (const float*)d_in[6];
    const float* Wk  = (const float*)d_in[7];
    const float* bk  = (const float*)d_in[8];
    const float* Wv  = (const float*)d_in[9];
    const float* bv  = (const float*)d_in[10];
    float* out = (float*)d_out;
    float* ws  = (float*)d_ws;

    // workspace layout (floats), all float4-aligned:
    float* pA     = ws;              // 16*64*1024 = 1048576
    float* q      = ws + 1048576;    // 16384
    float* qk     = ws + 1064960;    // 16384
    float* qbk    = ws + 1081344;    // 16 (padded to 1024)
    float* scores = ws + 1082368;    // 32768
    float* probas = ws + 1115136;    // 32768
    float* pC     = ws + 1147904;    // 1048576  -> total ~8.4 MB

    const dim3 gridBC(NCHUNK, BS);
    k1_hidden_partial<<<gridBC, 256, 0, stream>>>(hs, am, pA);
    k3_q<<<dim3(4, BS), 256, 0, stream>>>(pA, am, Wq, bq, q);
    k4_qk<<<dim3(4, BS), 256, 0, stream>>>(q, Wk, bk, qk, qbk);
    k5_scores<<<gridBC, 256, 0, stream>>>(emb, am, qk, qbk, scores);
    k6_softmax<<<BS, 256, 0, stream>>>(scores, am, fs, probas, out);
    k7_wemb<<<gridBC, 256, 0, stream>>>(emb, probas, pC);
    k8_combined<<<dim3(4, BS), 256, 0, stream>>>(pC, Wv, bv, out);
}

// Round 6
// 361.579 us; speedup vs baseline: 1.2173x; 1.2173x over previous
//
#include <hip/hip_runtime.h>

#define BS 16
#define TS 2048
#define H 1024
#define MT_LEN 1024
#define NCHUNK 64
#define CHUNK_T (TS / NCHUNK)   // 32
#define SCALE 0.03125f          // 1/sqrt(1024)
#define NEG -10000.0f

// ---------------- K1: partial masked sums of hidden_states over t ----------------
// grid (NCHUNK, BS), block 256; block covers full H via float4, CHUNK_T tokens.
__global__ __launch_bounds__(256)
void k1_hidden_partial(const float* __restrict__ hs,
                       const int* __restrict__ am,
                       float* __restrict__ pA) {
    const int c = blockIdx.x, b = blockIdx.y;
    const int tid = threadIdx.x;
    const int h4 = tid * 4;
    __shared__ float ms[CHUNK_T];
    if (tid < CHUNK_T) ms[tid] = (float)am[b * TS + c * CHUNK_T + tid];
    __syncthreads();
    const float* base = hs + ((size_t)(b * TS + c * CHUNK_T)) * H + h4;
    float4 acc = {0.f, 0.f, 0.f, 0.f};
#pragma unroll 4
    for (int t = 0; t < CHUNK_T; ++t) {
        const float m = ms[t];
        float4 v = *(const float4*)(base + (size_t)t * H);
        acc.x += m * v.x; acc.y += m * v.y; acc.z += m * v.z; acc.w += m * v.w;
    }
    *(float4*)(pA + ((size_t)(b * NCHUNK + c)) * H + h4) = acc;
}

// ---------------- K2: combine partials + mask count -> avg[b,h] ----------------
__global__ __launch_bounds__(256)
void k2_avg(const float* __restrict__ pA, const int* __restrict__ am,
            float* __restrict__ avg) {
    const int b = blockIdx.x;
    const int tid = threadIdx.x;
    __shared__ float red[256];
    int s = 0;
    for (int t = tid; t < TS; t += 256) s += am[b * TS + t];
    red[tid] = (float)s;
    __syncthreads();
    for (int o = 128; o > 0; o >>= 1) { if (tid < o) red[tid] += red[tid + o]; __syncthreads(); }
    const float inv = 1.0f / red[0];
    const int h4 = tid * 4;
    float4 acc = {0.f, 0.f, 0.f, 0.f};
    for (int c = 0; c < NCHUNK; ++c) {
        float4 v = *(const float4*)(pA + ((size_t)(b * NCHUNK + c)) * H + h4);
        acc.x += v.x; acc.y += v.y; acc.z += v.z; acc.w += v.w;
    }
    acc.x *= inv; acc.y *= inv; acc.z *= inv; acc.w *= inv;
    *(float4*)(avg + (size_t)b * H + h4) = acc;
}

// ---------------- K3: q[b,i] = Wq[i,:]·avg[b,:] + bq[i]  (wave-per-row, coalesced) ----------------
// grid (H/4, BS), block 256 = 4 waves; wave w -> row i = bx*4+w.
__global__ __launch_bounds__(256)
void k3_q(const float* __restrict__ avg, const float* __restrict__ Wq,
          const float* __restrict__ bq, float* __restrict__ q) {
    const int b = blockIdx.y;
    const int tid = threadIdx.x;
    __shared__ float avs[H];
    *(float4*)(&avs[tid * 4]) = *(const float4*)(avg + (size_t)b * H + tid * 4);
    __syncthreads();
    const int wave = tid >> 6, lane = tid & 63;
    const int i = blockIdx.x * 4 + wave;
    const float* row = Wq + (size_t)i * H;
    float acc = 0.f;
#pragma unroll
    for (int u = 0; u < 4; ++u) {
        const int j = u * 256 + lane * 4;          // lane*4 consecutive -> 1KB/instr coalesced
        float4 w = *(const float4*)(row + j);
        float4 a = *(const float4*)(&avs[j]);
        acc += w.x * a.x + w.y * a.y + w.z * a.z + w.w * a.w;
    }
#pragma unroll
    for (int o = 32; o > 0; o >>= 1) acc += __shfl_xor(acc, o);
    if (lane == 0) q[b * H + i] = acc + bq[i];
}

// ---------------- K4: qk partials over i-chunks; qbk partials ----------------
// grid (4 ic, BS), block 256; thread owns 4 consecutive j (float4 coalesced rows).
__global__ __launch_bounds__(256)
void k4_qkp(const float* __restrict__ q, const float* __restrict__ Wk,
            const float* __restrict__ bk, float* __restrict__ qk_p,
            float* __restrict__ qbk_p) {
    const int ic = blockIdx.x, b = blockIdx.y;
    const int tid = threadIdx.x;
    __shared__ float qs[256];
    __shared__ float red[256];
    qs[tid] = q[b * H + ic * 256 + tid];
    __syncthreads();
    const int j = tid * 4;
    float4 acc = {0.f, 0.f, 0.f, 0.f};
#pragma unroll 8
    for (int ii = 0; ii < 256; ++ii) {
        const float s = qs[ii];
        float4 w = *(const float4*)(Wk + ((size_t)(ic * 256 + ii)) * H + j);
        acc.x += s * w.x; acc.y += s * w.y; acc.z += s * w.z; acc.w += s * w.w;
    }
    *(float4*)(qk_p + ((size_t)(ic * BS + b)) * H + j) = acc;
    // qbk partial over this i-chunk
    red[tid] = qs[tid] * bk[ic * 256 + tid];
    __syncthreads();
    for (int o = 128; o > 0; o >>= 1) { if (tid < o) red[tid] += red[tid + o]; __syncthreads(); }
    if (tid == 0) qbk_p[ic * BS + b] = red[0];
}

// ---------------- K5: fused scores + online chunk softmax partials + weighted emb sum ----------------
// grid (NCHUNK, BS), block 256 = 4 waves; 32 tokens/chunk, 8 tokens/wave.
__global__ __launch_bounds__(256)
void k5_fused(const float* __restrict__ emb, const int* __restrict__ am,
              const float* __restrict__ qk_p, const float* __restrict__ qbk_p,
              float* __restrict__ scores, float* __restrict__ mc_arr,
              float* __restrict__ zc_arr, float* __restrict__ e_c) {
    const int c = blockIdx.x, b = blockIdx.y;
    const int tid = threadIdx.x;
    __shared__ float qks[H];
    __shared__ float sbuf[CHUNK_T];
    __shared__ float wbuf[CHUNK_T];
    // qk = sum of 4 i-chunk partials
    {
        const int j = tid * 4;
        float4 a = {0.f, 0.f, 0.f, 0.f};
#pragma unroll
        for (int ic = 0; ic < 4; ++ic) {
            float4 v = *(const float4*)(qk_p + ((size_t)(ic * BS + b)) * H + j);
            a.x += v.x; a.y += v.y; a.z += v.z; a.w += v.w;
        }
        *(float4*)(&qks[j]) = a;
    }
    const float qb = qbk_p[0 * BS + b] + qbk_p[1 * BS + b] + qbk_p[2 * BS + b] + qbk_p[3 * BS + b];
    __syncthreads();
    const int wave = tid >> 6, lane = tid & 63;
    // phase A: 8 token dots per wave
    for (int tt = 0; tt < 8; ++tt) {
        const int tl = wave * 8 + tt;
        const int t = c * CHUNK_T + tl;
        const float* e = emb + ((size_t)(b * TS + t)) * H;
        float acc = 0.f;
#pragma unroll
        for (int u = 0; u < 4; ++u) {
            const int j = u * 256 + lane * 4;
            float4 v = *(const float4*)(e + j);
            float4 a = *(const float4*)(&qks[j]);
            acc += v.x * a.x + v.y * a.y + v.z * a.z + v.w * a.w;
        }
#pragma unroll
        for (int o = 32; o > 0; o >>= 1) acc += __shfl_xor(acc, o);
        if (lane == 0) {
            const float sc = (am[b * TS + t] != 0) ? (acc + qb) * SCALE : NEG;
            scores[b * TS + t] = sc;
            sbuf[tl] = sc;
        }
    }
    __syncthreads();
    // chunk max (redundant broadcast reads)
    float mc = -3.4e38f;
#pragma unroll
    for (int tl = 0; tl < CHUNK_T; ++tl) mc = fmaxf(mc, sbuf[tl]);
    if (tid < CHUNK_T) wbuf[tid] = __expf(sbuf[tid] - mc);
    __syncthreads();
    float zc = 0.f;
#pragma unroll
    for (int tl = 0; tl < CHUNK_T; ++tl) zc += wbuf[tl];
    // phase B: weighted emb sum (chunk is L2/L3-hot from phase A)
    const int h4 = tid * 4;
    const float* base = emb + ((size_t)(b * TS + c * CHUNK_T)) * H + h4;
    float4 acc = {0.f, 0.f, 0.f, 0.f};
#pragma unroll 4
    for (int t = 0; t < CHUNK_T; ++t) {
        const float p = wbuf[t];
        float4 v = *(const float4*)(base + (size_t)t * H);
        acc.x += p * v.x; acc.y += p * v.y; acc.z += p * v.z; acc.w += p * v.w;
    }
    *(float4*)(e_c + ((size_t)(b * NCHUNK + c)) * H + h4) = acc;
    if (tid == 0) { mc_arr[b * NCHUNK + c] = mc; zc_arr[b * NCHUNK + c] = zc; }
}

// ---------------- K6: combine chunk stats -> m, invZ, e_comb[b,h] ----------------
__global__ __launch_bounds__(256)
void k6_combine(const float* __restrict__ mc_arr, const float* __restrict__ zc_arr,
                const float* __restrict__ e_c, float* __restrict__ e_comb,
                float* __restrict__ mz) {
    const int b = blockIdx.x;
    const int tid = threadIdx.x;
    __shared__ float mcs[NCHUNK], zcs[NCHUNK], scs[NCHUNK];
    if (tid < NCHUNK) { mcs[tid] = mc_arr[b * NCHUNK + tid]; zcs[tid] = zc_arr[b * NCHUNK + tid]; }
    __syncthreads();
    float m = -3.4e38f;
    for (int c = 0; c < NCHUNK; ++c) m = fmaxf(m, mcs[c]);
    float Z = 0.f;
    for (int c = 0; c < NCHUNK; ++c) Z += zcs[c] * __expf(mcs[c] - m);
    if (tid < NCHUNK) scs[tid] = __expf(mcs[tid] - m);
    __syncthreads();
    const float invZ = 1.0f / Z;
    const int h4 = tid * 4;
    float4 acc = {0.f, 0.f, 0.f, 0.f};
    for (int c = 0; c < NCHUNK; ++c) {
        const float s = scs[c];
        float4 v = *(const float4*)(e_c + ((size_t)(b * NCHUNK + c)) * H + h4);
        acc.x += s * v.x; acc.y += s * v.y; acc.z += s * v.z; acc.w += s * v.w;
    }
    acc.x *= invZ; acc.y *= invZ; acc.z *= invZ; acc.w *= invZ;
    *(float4*)(e_comb + (size_t)b * H + h4) = acc;
    if (tid == 0) { mz[b * 2] = m; mz[b * 2 + 1] = invZ; }
}

// ---------------- K7: probas outputs (mt / src) ----------------
__global__ __launch_bounds__(256)
void k7_probas(const float* __restrict__ scores, const float* __restrict__ mz,
               const int* __restrict__ am, const int* __restrict__ fs,
               float* __restrict__ out) {
    const int b = blockIdx.x;
    const int tid = threadIdx.x;
    const float m = mz[b * 2], invZ = mz[b * 2 + 1];
#pragma unroll
    for (int u = 0; u < 8; ++u) {
        const int t = tid + u * 256;
        const float p = __expf(scores[b * TS + t] - m) * invZ;
        const int a = am[b * TS + t];
        const int f = fs[b * TS + t];
        if (t < MT_LEN)
            out[BS * H + b * MT_LEN + t] = p * (float)(a * f);
        else
            out[BS * H + BS * MT_LEN + b * (TS - MT_LEN) + (t - MT_LEN)] = p * (float)(a * (1 - f));
    }
}

// ---------------- K8: combined[b,i] = Wv[i,:]·e_comb[b,:] + bv[i] (wave-per-row) ----------------
__global__ __launch_bounds__(256)
void k8_out(const float* __restrict__ e_comb, const float* __restrict__ Wv,
            const float* __restrict__ bv, float* __restrict__ out) {
    const int b = blockIdx.y;
    const int tid = threadIdx.x;
    __shared__ float es[H];
    *(float4*)(&es[tid * 4]) = *(const float4*)(e_comb + (size_t)b * H + tid * 4);
    __syncthreads();
    const int wave = tid >> 6, lane = tid & 63;
    const int i = blockIdx.x * 4 + wave;
    const float* row = Wv + (size_t)i * H;
    float acc = 0.f;
#pragma unroll
    for (int u = 0; u < 4; ++u) {
        const int j = u * 256 + lane * 4;
        float4 w = *(const float4*)(row + j);
        float4 a = *(const float4*)(&es[j]);
        acc += w.x * a.x + w.y * a.y + w.z * a.z + w.w * a.w;
    }
#pragma unroll
    for (int o = 32; o > 0; o >>= 1) acc += __shfl_xor(acc, o);
    if (lane == 0) out[b * H + i] = acc + bv[i];
}

extern "C" void kernel_launch(void* const* d_in, const int* in_sizes, int n_in,
                              void* d_out, int out_size, void* d_ws, size_t ws_size,
                              hipStream_t stream) {
    const float* hs  = (const float*)d_in[0];   // hidden_states (16,2048,1024)
    const float* emb = (const float*)d_in[1];   // embeddings    (16,2048,1024)
    const int*   am  = (const int*)d_in[2];     // attention_mask (16,2048)
    const int*   fs  = (const int*)d_in[3];     // first_sentence_mask (16,2048)
    // d_in[4]: first_piece_mask (unused)
    const float* Wq  = (const float*)d_in[5];
    const float* bq  = (const float*)d_in[6];
    const float* Wk  = (const float*)d_in[7];
    const float* bk  = (const float*)d_in[8];
    const float* Wv  = (const float*)d_in[9];
    const float* bv  = (const float*)d_in[10];
    float* out = (float*)d_out;
    float* ws  = (float*)d_ws;

    // workspace layout (floats), all 16B-aligned:
    float* pA     = ws;              // 16*64*1024 = 1048576
    float* avg    = ws + 1048576;    // 16384
    float* q      = ws + 1064960;    // 16384
    float* qk_p   = ws + 1081344;    // 4*16*1024 = 65536
    float* qbk_p  = ws + 1146880;    // 64 (pad 256)
    float* scores = ws + 1147136;    // 32768
    float* mc_arr = ws + 1179904;    // 1024
    float* zc_arr = ws + 1180928;    // 1024
    float* e_c    = ws + 1181952;    // 1048576
    float* mz     = ws + 2230528;    // 32 (pad 256)
    float* e_comb = ws + 2230784;    // 16384  -> total ~9 MB

    k1_hidden_partial<<<dim3(NCHUNK, BS), 256, 0, stream>>>(hs, am, pA);
    k2_avg<<<BS, 256, 0, stream>>>(pA, am, avg);
    k3_q<<<dim3(H / 4, BS), 256, 0, stream>>>(avg, Wq, bq, q);
    k4_qkp<<<dim3(4, BS), 256, 0, stream>>>(q, Wk, bk, qk_p, qbk_p);
    k5_fused<<<dim3(NCHUNK, BS), 256, 0, stream>>>(emb, am, qk_p, qbk_p,
                                                   scores, mc_arr, zc_arr, e_c);
    k6_combine<<<BS, 256, 0, stream>>>(mc_arr, zc_arr, e_c, e_comb, mz);
    k7_probas<<<BS, 256, 0, stream>>>(scores, mz, am, fs, out);
    k8_out<<<dim3(H / 4, BS), 256, 0, stream>>>(e_comb, Wv, bv, out);
}

// Round 7
// 353.992 us; speedup vs baseline: 1.2434x; 1.0214x over previous
//
#include <hip/hip_runtime.h>

#define BS 16
#define TS 2048
#define H 1024
#define MT_LEN 1024
#define NCHUNK 64
#define CHUNK_T (TS / NCHUNK)   // 32 (k1)
#define NC5 128
#define T5 (TS / NC5)           // 16 (k5)
#define SCALE 0.03125f          // 1/sqrt(1024)
#define NEG -10000.0f

// ---------------- K1: partial masked sums of hidden_states over t ----------------
__global__ __launch_bounds__(256)
void k1_hidden_partial(const float* __restrict__ hs,
                       const int* __restrict__ am,
                       float* __restrict__ pA) {
    const int c = blockIdx.x, b = blockIdx.y;
    const int tid = threadIdx.x;
    const int h4 = tid * 4;
    __shared__ float ms[CHUNK_T];
    if (tid < CHUNK_T) ms[tid] = (float)am[b * TS + c * CHUNK_T + tid];
    __syncthreads();
    const float* base = hs + ((size_t)(b * TS + c * CHUNK_T)) * H + h4;
    float4 acc = {0.f, 0.f, 0.f, 0.f};
#pragma unroll 4
    for (int t = 0; t < CHUNK_T; ++t) {
        const float m = ms[t];
        float4 v = *(const float4*)(base + (size_t)t * H);
        acc.x += m * v.x; acc.y += m * v.y; acc.z += m * v.z; acc.w += m * v.w;
    }
    *(float4*)(pA + ((size_t)(b * NCHUNK + c)) * H + h4) = acc;
}

// ---------------- K2: combine partials + mask count -> avg[b,h] ----------------
__global__ __launch_bounds__(256)
void k2_avg(const float* __restrict__ pA, const int* __restrict__ am,
            float* __restrict__ avg) {
    const int b = blockIdx.x;
    const int tid = threadIdx.x;
    __shared__ float red[256];
    int s = 0;
    for (int t = tid; t < TS; t += 256) s += am[b * TS + t];
    red[tid] = (float)s;
    __syncthreads();
    for (int o = 128; o > 0; o >>= 1) { if (tid < o) red[tid] += red[tid + o]; __syncthreads(); }
    const float inv = 1.0f / red[0];
    const int h4 = tid * 4;
    float4 acc = {0.f, 0.f, 0.f, 0.f};
    for (int c = 0; c < NCHUNK; ++c) {
        float4 v = *(const float4*)(pA + ((size_t)(b * NCHUNK + c)) * H + h4);
        acc.x += v.x; acc.y += v.y; acc.z += v.z; acc.w += v.w;
    }
    acc.x *= inv; acc.y *= inv; acc.z *= inv; acc.w *= inv;
    *(float4*)(avg + (size_t)b * H + h4) = acc;
}

// ---------------- K3: q[b,i] = Wq[i,:]·avg[b,:] + bq[i]  (wave-per-row, coalesced) ----------------
__global__ __launch_bounds__(256)
void k3_q(const float* __restrict__ avg, const float* __restrict__ Wq,
          const float* __restrict__ bq, float* __restrict__ q) {
    const int b = blockIdx.y;
    const int tid = threadIdx.x;
    __shared__ float avs[H];
    *(float4*)(&avs[tid * 4]) = *(const float4*)(avg + (size_t)b * H + tid * 4);
    __syncthreads();
    const int wave = tid >> 6, lane = tid & 63;
    const int i = blockIdx.x * 4 + wave;
    const float* row = Wq + (size_t)i * H;
    float acc = 0.f;
#pragma unroll
    for (int u = 0; u < 4; ++u) {
        const int j = u * 256 + lane * 4;
        float4 w = *(const float4*)(row + j);
        float4 a = *(const float4*)(&avs[j]);
        acc += w.x * a.x + w.y * a.y + w.z * a.z + w.w * a.w;
    }
#pragma unroll
    for (int o = 32; o > 0; o >>= 1) acc += __shfl_xor(acc, o);
    if (lane == 0) q[b * H + i] = acc + bq[i];
}

// ---------------- K4: qk partials over i-chunks; qbk partials ----------------
__global__ __launch_bounds__(256)
void k4_qkp(const float* __restrict__ q, const float* __restrict__ Wk,
            const float* __restrict__ bk, float* __restrict__ qk_p,
            float* __restrict__ qbk_p) {
    const int ic = blockIdx.x, b = blockIdx.y;
    const int tid = threadIdx.x;
    __shared__ float qs[256];
    __shared__ float red[256];
    qs[tid] = q[b * H + ic * 256 + tid];
    __syncthreads();
    const int j = tid * 4;
    float4 acc = {0.f, 0.f, 0.f, 0.f};
#pragma unroll 8
    for (int ii = 0; ii < 256; ++ii) {
        const float s = qs[ii];
        float4 w = *(const float4*)(Wk + ((size_t)(ic * 256 + ii)) * H + j);
        acc.x += s * w.x; acc.y += s * w.y; acc.z += s * w.z; acc.w += s * w.w;
    }
    *(float4*)(qk_p + ((size_t)(ic * BS + b)) * H + j) = acc;
    red[tid] = qs[tid] * bk[ic * 256 + tid];
    __syncthreads();
    for (int o = 128; o > 0; o >>= 1) { if (tid < o) red[tid] += red[tid + o]; __syncthreads(); }
    if (tid == 0) qbk_p[ic * BS + b] = red[0];
}

// ---------------- K5: LDS-staged fused scores + chunk softmax stats + weighted emb sum ----------------
// grid (NC5, BS), block 256 = 4 waves; 16 tokens/block staged once into LDS (64 KB).
// emb read from HBM exactly once; dots and weighted-sum both served from LDS.
__global__ __launch_bounds__(256)
void k5_fused(const float* __restrict__ emb, const int* __restrict__ am,
              const float* __restrict__ qk_p, const float* __restrict__ qbk_p,
              float* __restrict__ scores, float* __restrict__ mc_arr,
              float* __restrict__ zc_arr, float* __restrict__ e_c) {
    const int c = blockIdx.x, b = blockIdx.y;
    const int tid = threadIdx.x;
    __shared__ float qks[H];          // 4 KB
    __shared__ float ebuf[T5][H];     // 64 KB
    __shared__ float sbuf[T5];
    __shared__ float wbuf[T5];
    // qk = sum of 4 i-chunk partials
    {
        const int j = tid * 4;
        float4 a = {0.f, 0.f, 0.f, 0.f};
#pragma unroll
        for (int ic = 0; ic < 4; ++ic) {
            float4 v = *(const float4*)(qk_p + ((size_t)(ic * BS + b)) * H + j);
            a.x += v.x; a.y += v.y; a.z += v.z; a.w += v.w;
        }
        *(float4*)(&qks[j]) = a;
    }
    const float qb = qbk_p[0 * BS + b] + qbk_p[1 * BS + b] + qbk_p[2 * BS + b] + qbk_p[3 * BS + b];
    // stage 16 token rows (64 KB contiguous) into LDS, coalesced float4
    const float* src = emb + ((size_t)(b * TS + c * T5)) * H;
#pragma unroll
    for (int r = 0; r < T5; ++r) {
        *(float4*)(&ebuf[r][tid * 4]) = *(const float4*)(src + (size_t)r * H + tid * 4);
    }
    __syncthreads();
    const int wave = tid >> 6, lane = tid & 63;
    // hoist this lane's qk fragment to registers (halves LDS traffic in dot phase)
    float4 qr[4];
#pragma unroll
    for (int u = 0; u < 4; ++u) qr[u] = *(const float4*)(&qks[u * 256 + lane * 4]);
    // phase A: 4 token dots per wave, from LDS
    for (int tt = 0; tt < 4; ++tt) {
        const int tl = wave * 4 + tt;
        float acc = 0.f;
#pragma unroll
        for (int u = 0; u < 4; ++u) {
            float4 v = *(const float4*)(&ebuf[tl][u * 256 + lane * 4]);
            acc += v.x * qr[u].x + v.y * qr[u].y + v.z * qr[u].z + v.w * qr[u].w;
        }
#pragma unroll
        for (int o = 32; o > 0; o >>= 1) acc += __shfl_xor(acc, o);
        if (lane == 0) {
            const int t = c * T5 + tl;
            const float sc = (am[b * TS + t] != 0) ? (acc + qb) * SCALE : NEG;
            scores[b * TS + t] = sc;
            sbuf[tl] = sc;
        }
    }
    __syncthreads();
    // chunk max / exp / partial Z (broadcast reads, conflict-free)
    float mc = -3.4e38f;
#pragma unroll
    for (int tl = 0; tl < T5; ++tl) mc = fmaxf(mc, sbuf[tl]);
    if (tid < T5) wbuf[tid] = __expf(sbuf[tid] - mc);
    __syncthreads();
    float zc = 0.f;
#pragma unroll
    for (int tl = 0; tl < T5; ++tl) zc += wbuf[tl];
    // phase B: weighted sum from LDS (no global reread)
    const int h4 = tid * 4;
    float4 acc = {0.f, 0.f, 0.f, 0.f};
#pragma unroll
    for (int t = 0; t < T5; ++t) {
        const float p = wbuf[t];
        float4 v = *(const float4*)(&ebuf[t][h4]);
        acc.x += p * v.x; acc.y += p * v.y; acc.z += p * v.z; acc.w += p * v.w;
    }
    *(float4*)(e_c + ((size_t)(b * NC5 + c)) * H + h4) = acc;
    if (tid == 0) { mc_arr[b * NC5 + c] = mc; zc_arr[b * NC5 + c] = zc; }
}

// ---------------- K6: combine chunk stats -> e_comb[b,h]; write probas outputs (fused old k6+k7) ----------------
__global__ __launch_bounds__(256)
void k6_finish(const float* __restrict__ mc_arr, const float* __restrict__ zc_arr,
               const float* __restrict__ e_c, const float* __restrict__ scores,
               const int* __restrict__ am, const int* __restrict__ fs,
               float* __restrict__ e_comb, float* __restrict__ out) {
    const int b = blockIdx.x;
    const int tid = threadIdx.x;
    __shared__ float mcs[NC5], zcs[NC5], scs[NC5];
    if (tid < NC5) { mcs[tid] = mc_arr[b * NC5 + tid]; zcs[tid] = zc_arr[b * NC5 + tid]; }
    __syncthreads();
    float m = -3.4e38f;
    for (int c = 0; c < NC5; ++c) m = fmaxf(m, mcs[c]);
    float Z = 0.f;
    for (int c = 0; c < NC5; ++c) Z += zcs[c] * __expf(mcs[c] - m);
    if (tid < NC5) scs[tid] = __expf(mcs[tid] - m);
    __syncthreads();
    const float invZ = 1.0f / Z;
    // e_comb
    const int h4 = tid * 4;
    float4 acc = {0.f, 0.f, 0.f, 0.f};
    for (int c = 0; c < NC5; ++c) {
        const float s = scs[c];
        float4 v = *(const float4*)(e_c + ((size_t)(b * NC5 + c)) * H + h4);
        acc.x += s * v.x; acc.y += s * v.y; acc.z += s * v.z; acc.w += s * v.w;
    }
    acc.x *= invZ; acc.y *= invZ; acc.z *= invZ; acc.w *= invZ;
    *(float4*)(e_comb + (size_t)b * H + h4) = acc;
    // probas outputs (mt / src)
#pragma unroll
    for (int u = 0; u < 8; ++u) {
        const int t = tid + u * 256;
        const float p = __expf(scores[b * TS + t] - m) * invZ;
        const int a = am[b * TS + t];
        const int f = fs[b * TS + t];
        if (t < MT_LEN)
            out[BS * H + b * MT_LEN + t] = p * (float)(a * f);
        else
            out[BS * H + BS * MT_LEN + b * (TS - MT_LEN) + (t - MT_LEN)] = p * (float)(a * (1 - f));
    }
}

// ---------------- K8: combined[b,i] = Wv[i,:]·e_comb[b,:] + bv[i] (wave-per-row) ----------------
__global__ __launch_bounds__(256)
void k8_out(const float* __restrict__ e_comb, const float* __restrict__ Wv,
            const float* __restrict__ bv, float* __restrict__ out) {
    const int b = blockIdx.y;
    const int tid = threadIdx.x;
    __shared__ float es[H];
    *(float4*)(&es[tid * 4]) = *(const float4*)(e_comb + (size_t)b * H + tid * 4);
    __syncthreads();
    const int wave = tid >> 6, lane = tid & 63;
    const int i = blockIdx.x * 4 + wave;
    const float* row = Wv + (size_t)i * H;
    float acc = 0.f;
#pragma unroll
    for (int u = 0; u < 4; ++u) {
        const int j = u * 256 + lane * 4;
        float4 w = *(const float4*)(row + j);
        float4 a = *(const float4*)(&es[j]);
        acc += w.x * a.x + w.y * a.y + w.z * a.z + w.w * a.w;
    }
#pragma unroll
    for (int o = 32; o > 0; o >>= 1) acc += __shfl_xor(acc, o);
    if (lane == 0) out[b * H + i] = acc + bv[i];
}

extern "C" void kernel_launch(void* const* d_in, const int* in_sizes, int n_in,
                              void* d_out, int out_size, void* d_ws, size_t ws_size,
                              hipStream_t stream) {
    const float* hs  = (const float*)d_in[0];   // hidden_states (16,2048,1024)
    const float* emb = (const float*)d_in[1];   // embeddings    (16,2048,1024)
    const int*   am  = (const int*)d_in[2];     // attention_mask (16,2048)
    const int*   fs  = (const int*)d_in[3];     // first_sentence_mask (16,2048)
    // d_in[4]: first_piece_mask (unused)
    const float* Wq  = (const float*)d_in[5];
    const float* bq  = (const float*)d_in[6];
    const float* Wk  = (const float*)d_in[7];
    const float* bk  = (const float*)d_in[8];
    const float* Wv  = (const float*)d_in[9];
    const float* bv  = (const float*)d_in[10];
    float* out = (float*)d_out;
    float* ws  = (float*)d_ws;

    // workspace layout (floats), all 16B-aligned:
    float* pA     = ws;              // 16*64*1024 = 1048576
    float* avg    = ws + 1048576;    // 16384
    float* q      = ws + 1064960;    // 16384
    float* qk_p   = ws + 1081344;    // 4*16*1024 = 65536
    float* qbk_p  = ws + 1146880;    // 64 (pad 256)
    float* scores = ws + 1147136;    // 32768
    float* mc_arr = ws + 1179904;    // 16*128 = 2048
    float* zc_arr = ws + 1181952;    // 2048
    float* e_c    = ws + 1184000;    // 16*128*1024 = 2097152
    float* e_comb = ws + 3281152;    // 16384  -> total ~13.2 MB

    k1_hidden_partial<<<dim3(NCHUNK, BS), 256, 0, stream>>>(hs, am, pA);
    k2_avg<<<BS, 256, 0, stream>>>(pA, am, avg);
    k3_q<<<dim3(H / 4, BS), 256, 0, stream>>>(avg, Wq, bq, q);
    k4_qkp<<<dim3(4, BS), 256, 0, stream>>>(q, Wk, bk, qk_p, qbk_p);
    k5_fused<<<dim3(NC5, BS), 256, 0, stream>>>(emb, am, qk_p, qbk_p,
                                                scores, mc_arr, zc_arr, e_c);
    k6_finish<<<BS, 256, 0, stream>>>(mc_arr, zc_arr, e_c, scores, am, fs, e_comb, out);
    k8_out<<<dim3(H / 4, BS), 256, 0, stream>>>(e_comb, Wv, bv, out);
}